// Round 4
// baseline (211.719 us; speedup 1.0000x reference)
//
#include <hip/hip_runtime.h>

typedef __bf16 bf16;
typedef __bf16 bf16x2 __attribute__((ext_vector_type(2)));
typedef __bf16 bf16x4 __attribute__((ext_vector_type(4)));
typedef __bf16 bf16x8 __attribute__((ext_vector_type(8)));
typedef float  f32x4  __attribute__((ext_vector_type(4)));

#define S_LEN 1863
#define S_PAD 1920
#define DM 1024
#define NH 16
#define HDIM 64
#define AUGD 160      // 64 qk dims + 32 x-onehot + 32 y-onehot + 32 z-onehot
#define QKV_STRIDE 3072
#define NQT128 15     // ceil(S/128)
#define CHUNK 8       // k-tiles (of 64 keys) per split-K block
#define MAXC 4        // max chunks per q-tile (ceil(30/8))

#define MFMA_BF16 __builtin_amdgcn_mfma_f32_16x16x32_bf16

// ---------------------------------------------------------------------------
// fused fp32->bf16 conversion of x, Wqkv, Wout
// ---------------------------------------------------------------------------
__global__ void cvt3(const float* __restrict__ a, bf16* __restrict__ oa, int na4,
                     const float* __restrict__ b, bf16* __restrict__ ob, int nb4,
                     const float* __restrict__ c, bf16* __restrict__ oc, int nc4) {
  int j = blockIdx.x * blockDim.x + threadIdx.x;
  const float* s; bf16* d;
  if (j < na4) { s = a; d = oa; }
  else {
    j -= na4;
    if (j < nb4) { s = b; d = ob; }
    else { j -= nb4; if (j >= nc4) return; s = c; d = oc; }
  }
  float4 v = ((const float4*)s)[j];
  bf16x4 o;
  o[0] = (bf16)v.x; o[1] = (bf16)v.y; o[2] = (bf16)v.z; o[3] = (bf16)v.w;
  ((bf16x4*)d)[j] = o;
}

// ---------------------------------------------------------------------------
// bf16 MFMA GEMM, 128x64 tile (more blocks -> latency overlap), BK=32, 4 waves.
// Wave w: m-half wm=w>>1 (64 rows), n-half wn=w&1 (32 cols) -> 4x2 MFMA frags.
// ---------------------------------------------------------------------------
template <typename T>
__global__ __launch_bounds__(256) void gemm_bt(const bf16* __restrict__ A,
                                               const bf16* __restrict__ B,
                                               T* __restrict__ C,
                                               int M, int N, int K) {
  __shared__ bf16 As[128][40];
  __shared__ bf16 Bs[64][40];
  const int t = threadIdx.x;
  const int w = t >> 6, l = t & 63;
  const int quad = l >> 4, l16 = l & 15;
  const int wm = w >> 1, wn = w & 1;
  const int bm = blockIdx.y * 128, bn = blockIdx.x * 64;

  f32x4 acc[4][2];
#pragma unroll
  for (int mi = 0; mi < 4; ++mi)
#pragma unroll
    for (int ni = 0; ni < 2; ++ni) acc[mi][ni] = 0;

  const int srow = t >> 2;
  const int sk8  = (t & 3) * 8;

  for (int k0 = 0; k0 < K; k0 += 32) {
    bf16x8 a0 = *(const bf16x8*)&A[(size_t)min(bm + srow,      M - 1) * K + k0 + sk8];
    bf16x8 a1 = *(const bf16x8*)&A[(size_t)min(bm + srow + 64, M - 1) * K + k0 + sk8];
    bf16x8 b0 = *(const bf16x8*)&B[(size_t)(bn + srow) * K + k0 + sk8];
    __syncthreads();
    *(bf16x8*)&As[srow][sk8]      = a0;
    *(bf16x8*)&As[srow + 64][sk8] = a1;
    *(bf16x8*)&Bs[srow][sk8]      = b0;
    __syncthreads();

    bf16x8 af[4], bfr[2];
#pragma unroll
    for (int mi = 0; mi < 4; ++mi) af[mi]  = *(bf16x8*)&As[wm * 64 + mi * 16 + l16][quad * 8];
#pragma unroll
    for (int ni = 0; ni < 2; ++ni) bfr[ni] = *(bf16x8*)&Bs[wn * 32 + ni * 16 + l16][quad * 8];
#pragma unroll
    for (int mi = 0; mi < 4; ++mi)
#pragma unroll
      for (int ni = 0; ni < 2; ++ni)
        acc[mi][ni] = MFMA_BF16(af[mi], bfr[ni], acc[mi][ni], 0, 0, 0);
  }

#pragma unroll
  for (int mi = 0; mi < 4; ++mi)
#pragma unroll
    for (int r = 0; r < 4; ++r) {
      int m = bm + wm * 64 + mi * 16 + quad * 4 + r;
      if (m < M) {
#pragma unroll
        for (int ni = 0; ni < 2; ++ni)
          C[(size_t)m * N + bn + wn * 32 + ni * 16 + l16] = (T)acc[mi][ni][r];
      }
    }
}

// ---------------------------------------------------------------------------
// Build augmented Q/K: dims [0,64)=RoPE'd q*0.125 / k; [64,96)=Gx / onehot(px);
// [96,128)=Gy / onehot(py); [128,160)=Gz / onehot(pz).
// Gx[i][b] = bias_x[clip(px_i - b, +-30)+30][h] etc. (z uses RAW pz for bias,
// clipped pz for rope, exactly like the reference). Then Qa . Ka over 160 dims
// = qk/8 + bx + by + bz -- the whole bias rides the MFMA.
// ---------------------------------------------------------------------------
__global__ __launch_bounds__(512) void pack_aug(const bf16* __restrict__ qkv,
                                                const int* __restrict__ pos,
                                                const float* __restrict__ bxg,
                                                const float* __restrict__ byg,
                                                const float* __restrict__ bzg,
                                                bf16* __restrict__ Qa,
                                                bf16* __restrict__ Ka) {
  const int s = blockIdx.x;
  const int t = threadIdx.x;
  const int h = t >> 5, sub = t & 31;
  const int px = pos[s * 3 + 0], py = pos[s * 3 + 1], pz = pos[s * 3 + 2];

  // --- RoPE pair `sub` ---
  int j, P, pp;
  if (sub < 10)      { j = sub;      P = 10; pp = min(max(px, 0), 31); }
  else if (sub < 20) { j = sub - 10; P = 10; pp = min(max(py, 0), 31); }
  else               { j = sub - 20; P = 12; pp = min(max(pz, 0), 7);  }
  const float inv = expf(-(float)j / (float)P * 9.210340371976184f);
  const float ang = (float)pp * inv;
  const float cs = cosf(ang), sn = sinf(ang);
  const size_t base = (size_t)s * QKV_STRIDE + h * HDIM + 2 * sub;
  bf16x2 q2 = *(const bf16x2*)&qkv[base];
  bf16x2 k2 = *(const bf16x2*)&qkv[base + DM];
  float q0 = (float)q2[0], q1 = (float)q2[1];
  float k0 = (float)k2[0], k1 = (float)k2[1];
  const size_t rb = ((size_t)h * S_PAD + s) * AUGD;
  bf16x2 oq, ok;
  oq[0] = (bf16)((q0 * cs - q1 * sn) * 0.125f);
  oq[1] = (bf16)((q1 * cs + q0 * sn) * 0.125f);
  ok[0] = (bf16)(k0 * cs - k1 * sn);
  ok[1] = (bf16)(k1 * cs + k0 * sn);
  *(bf16x2*)&Qa[rb + 2 * sub] = oq;
  *(bf16x2*)&Ka[rb + 2 * sub] = ok;

  // --- bias augmentation ---
  const int ix = min(max(px - sub, -30), 30) + 30;
  const int iy = min(max(py - sub, -30), 30) + 30;
  const int iz = min(max(pz - sub, -8), 8) + 8;
  Qa[rb + 64 + sub]  = (bf16)bxg[ix * NH + h];
  Qa[rb + 96 + sub]  = (bf16)byg[iy * NH + h];
  Qa[rb + 128 + sub] = (bf16)bzg[iz * NH + h];
  Ka[rb + 64 + sub]  = (bf16)(sub == px ? 1.0f : 0.0f);
  Ka[rb + 96 + sub]  = (bf16)(sub == py ? 1.0f : 0.0f);
  Ka[rb + 128 + sub] = (bf16)(sub == pz ? 1.0f : 0.0f);
}

// ---------------------------------------------------------------------------
// V -> transposed head-major: Vt[h][d][s(S_PAD)] via LDS tile transpose.
// ---------------------------------------------------------------------------
__global__ __launch_bounds__(256) void pack_v(const bf16* __restrict__ qkv,
                                              bf16* __restrict__ Vt) {
  const int st = blockIdx.x, h = blockIdx.y;
  const int t = threadIdx.x;
  __shared__ float tile[64][68];
  for (int i = t; i < 1024; i += 256) {
    int row = i >> 4, c4 = (i & 15) * 4;
    int sg = min(st * 64 + row, S_LEN - 1);
    bf16x4 v = *(const bf16x4*)&qkv[(size_t)sg * QKV_STRIDE + 2 * DM + h * HDIM + c4];
    *(float4*)&tile[row][c4] = make_float4((float)v[0], (float)v[1], (float)v[2], (float)v[3]);
  }
  __syncthreads();
  for (int i = t; i < 1024; i += 256) {
    int d = i >> 4, s4 = (i & 15) * 4;
    bf16x4 o;
    o[0] = (bf16)tile[s4 + 0][d];
    o[1] = (bf16)tile[s4 + 1][d];
    o[2] = (bf16)tile[s4 + 2][d];
    o[3] = (bf16)tile[s4 + 3][d];
    *(bf16x4*)&Vt[((size_t)h * HDIM + d) * S_PAD + st * 64 + s4] = o;
  }
}

// ---------------------------------------------------------------------------
// Split-K MFMA attention. Block = (chunk, 128-row q-tile, head); 4 waves, wave
// w owns q-rows w*32..+31 (2 m-frags). Scores INCLUDE bias via the 160-dim
// augmented QK MFMA. Fixed-m softmax (scores ~ +-3, exp safe; partials
// directly summable). No position / bias tables needed in-kernel at all.
// ---------------------------------------------------------------------------
__global__ __launch_bounds__(256) void attn_split(const bf16* __restrict__ Qa,
                                                  const bf16* __restrict__ Ka,
                                                  const bf16* __restrict__ Vt,
                                                  bf16* __restrict__ outb,
                                                  float* __restrict__ Opart,
                                                  float* __restrict__ lpart) {
  const int c = blockIdx.x;
  const int qt = NQT128 - 1 - blockIdx.y;  // longest chains dispatch first
  const int h = blockIdx.z;
  const int chain = 2 * qt + 2;            // k-tiles of 64 keys up to diagonal
  const int k0 = c * CHUNK;
  if (k0 >= chain) return;
  const int kend = min(k0 + CHUNK, chain);

  const int t = threadIdx.x, w = t >> 6, l = t & 63;
  const int quad = l >> 4, l16 = l & 15;

  __shared__ bf16 Ks[64][168];   // 64 keys x 160 aug dims (stride 336B: 2-way)
  __shared__ bf16 Vs[64][72];    // [dim][key]
  __shared__ bf16 Ps[4][32][72]; // wave-private P (32 q-rows x 64 keys)

  // Q fragments straight from global (once per block; L2-resident)
  bf16x8 aq[2][5];
  int ig[2][4];
#pragma unroll
  for (int mi = 0; mi < 2; ++mi) {
    const int qrow = qt * 128 + w * 32 + mi * 16 + l16;
    const bf16* qp = &Qa[((size_t)h * S_PAD + qrow) * AUGD + quad * 8];
#pragma unroll
    for (int sg = 0; sg < 5; ++sg) aq[mi][sg] = *(const bf16x8*)(qp + sg * 32);
#pragma unroll
    for (int r = 0; r < 4; ++r) ig[mi][r] = qt * 128 + w * 32 + mi * 16 + quad * 4 + r;
  }

  f32x4 O[2][4];
#pragma unroll
  for (int mi = 0; mi < 2; ++mi)
#pragma unroll
    for (int di = 0; di < 4; ++di) O[mi][di] = 0;
  float lacc[2][4] = {};

  for (int kt = k0; kt < kend; ++kt) {
    __syncthreads();
    // stage K (64 x 160 bf16) and V^T (64 x 64)
    for (int i = t; i < 1280; i += 256) {
      int row = i / 20, c8 = (i - row * 20) * 8;
      *(bf16x8*)&Ks[row][c8] =
          *(const bf16x8*)&Ka[((size_t)h * S_PAD + kt * 64 + row) * AUGD + c8];
    }
    for (int i = t; i < 512; i += 256) {
      int row = i >> 3, c8 = (i & 7) * 8;
      *(bf16x8*)&Vs[row][c8] =
          *(const bf16x8*)&Vt[((size_t)h * HDIM + row) * S_PAD + kt * 64 + c8];
    }
    __syncthreads();

    // ---- S = Qaug Kaug^T (includes bias) ----
    f32x4 sf[2][4];
#pragma unroll
    for (int ni = 0; ni < 4; ++ni) {
      bf16x8 bk[5];
      const bf16* kp = &Ks[ni * 16 + l16][quad * 8];
#pragma unroll
      for (int sg = 0; sg < 5; ++sg) bk[sg] = *(const bf16x8*)(kp + sg * 32);
#pragma unroll
      for (int mi = 0; mi < 2; ++mi) {
        f32x4 z = {0.f, 0.f, 0.f, 0.f};
#pragma unroll
        for (int sg = 0; sg < 5; ++sg) z = MFMA_BF16(aq[mi][sg], bk[sg], z, 0, 0, 0);
        sf[mi][ni] = z;
      }
    }

    // ---- exp + causal mask (diagonal-overlap tiles only), P -> wave LDS ----
#pragma unroll
    for (int mi = 0; mi < 2; ++mi) {
      const bool msk = (kt * 64 + 63) > (qt * 128 + w * 32 + mi * 16);
#pragma unroll
      for (int ni = 0; ni < 4; ++ni) {
        const int jg = kt * 64 + ni * 16 + l16;
#pragma unroll
        for (int r = 0; r < 4; ++r) {
          float p = __expf(sf[mi][ni][r]);
          if (msk && jg > ig[mi][r]) p = 0.f;
          lacc[mi][r] += p;
          Ps[w][mi * 16 + quad * 4 + r][ni * 16 + l16] = (bf16)p;
        }
      }
    }

    // ---- O += P V (wave-private LDS round-trip; no barrier needed) ----
    bf16x8 ap[2][2];
#pragma unroll
    for (int mi = 0; mi < 2; ++mi)
#pragma unroll
      for (int sg = 0; sg < 2; ++sg)
        ap[mi][sg] = *(bf16x8*)&Ps[w][mi * 16 + l16][sg * 32 + quad * 8];
#pragma unroll
    for (int di = 0; di < 4; ++di) {
      bf16x8 bv0 = *(bf16x8*)&Vs[di * 16 + l16][quad * 8];
      bf16x8 bv1 = *(bf16x8*)&Vs[di * 16 + l16][32 + quad * 8];
#pragma unroll
      for (int mi = 0; mi < 2; ++mi) {
        O[mi][di] = MFMA_BF16(ap[mi][0], bv0, O[mi][di], 0, 0, 0);
        O[mi][di] = MFMA_BF16(ap[mi][1], bv1, O[mi][di], 0, 0, 0);
      }
    }
  }

  // reduce l across the 16 lanes of each row
#pragma unroll
  for (int mi = 0; mi < 2; ++mi)
#pragma unroll
    for (int r = 0; r < 4; ++r) {
      float v = lacc[mi][r];
      v += __shfl_xor(v, 1);
      v += __shfl_xor(v, 2);
      v += __shfl_xor(v, 4);
      v += __shfl_xor(v, 8);
      lacc[mi][r] = v;
    }

  if (k0 == 0 && kend == chain) {
    // single chunk: finalize directly
#pragma unroll
    for (int mi = 0; mi < 2; ++mi)
#pragma unroll
      for (int r = 0; r < 4; ++r) {
        const int row = ig[mi][r];
        if (row < S_LEN) {
          const float inv = 1.0f / lacc[mi][r];
#pragma unroll
          for (int di = 0; di < 4; ++di)
            outb[(size_t)row * DM + h * HDIM + di * 16 + l16] = (bf16)(O[mi][di][r] * inv);
        }
      }
  } else {
    float* ob = Opart + (((size_t)h * NQT128 + qt) * MAXC + c) * 8192;
#pragma unroll
    for (int mi = 0; mi < 2; ++mi)
#pragma unroll
      for (int r = 0; r < 4; ++r) {
        const int row32 = w * 32 + mi * 16 + quad * 4 + r;
#pragma unroll
        for (int di = 0; di < 4; ++di)
          ob[row32 * 64 + di * 16 + l16] = O[mi][di][r];
      }
    if (l16 == 0) {
      float* lb = lpart + (((size_t)h * NQT128 + qt) * MAXC + c) * 128;
#pragma unroll
      for (int mi = 0; mi < 2; ++mi)
#pragma unroll
        for (int r = 0; r < 4; ++r) lb[w * 32 + mi * 16 + quad * 4 + r] = lacc[mi][r];
    }
  }
}

// ---------------------------------------------------------------------------
// Combine split-K partials for q-tiles with >1 chunk (qt >= 4).
// ---------------------------------------------------------------------------
__global__ __launch_bounds__(256) void attn_combine(const float* __restrict__ Opart,
                                                    const float* __restrict__ lpart,
                                                    bf16* __restrict__ outb) {
  const int qt = blockIdx.x + 4;
  const int h = blockIdx.y;
  const int t = threadIdx.x;
  const int row = t >> 1, half = t & 1;
  const int nchunk = (2 * qt + 2 + CHUNK - 1) / CHUNK;
  float4 acc[8];
#pragma unroll
  for (int j = 0; j < 8; ++j) acc[j] = make_float4(0.f, 0.f, 0.f, 0.f);
  float lsum = 0.f;
  const size_t pb = ((size_t)h * NQT128 + qt) * MAXC;
  for (int cc = 0; cc < nchunk; ++cc) {
    const float4* p4 = (const float4*)(Opart + (pb + cc) * 8192 + row * 64 + half * 32);
#pragma unroll
    for (int j = 0; j < 8; ++j) {
      float4 v = p4[j];
      acc[j].x += v.x; acc[j].y += v.y; acc[j].z += v.z; acc[j].w += v.w;
    }
    lsum += lpart[(pb + cc) * 128 + row];
  }
  const int s = qt * 128 + row;
  if (s < S_LEN) {
    const float inv = 1.0f / lsum;
    bf16* op = outb + (size_t)s * DM + h * HDIM + half * 32;
#pragma unroll
    for (int j = 0; j < 8; ++j) {
      bf16x4 o;
      o[0] = (bf16)(acc[j].x * inv);
      o[1] = (bf16)(acc[j].y * inv);
      o[2] = (bf16)(acc[j].z * inv);
      o[3] = (bf16)(acc[j].w * inv);
      *(bf16x4*)&op[j * 4] = o;
    }
  }
}

// ---------------------------------------------------------------------------
extern "C" void kernel_launch(void* const* d_in, const int* in_sizes, int n_in,
                              void* d_out, int out_size, void* d_ws, size_t ws_size,
                              hipStream_t stream) {
  const float* x    = (const float*)d_in[0];
  const float* Wqkv = (const float*)d_in[1];
  const float* Wout = (const float*)d_in[2];
  const float* bx   = (const float*)d_in[3];
  const float* by   = (const float*)d_in[4];
  const float* bz   = (const float*)d_in[5];
  const int*   pos  = (const int*)d_in[6];
  float* out = (float*)d_out;

  char* ws = (char*)d_ws;
  bf16* qkvb  = (bf16*)ws;   ws += (size_t)S_LEN * QKV_STRIDE * 2;
  bf16* xb    = (bf16*)ws;   ws += (size_t)S_LEN * DM * 2;
  bf16* wqkvb = (bf16*)ws;   ws += (size_t)QKV_STRIDE * DM * 2;
  bf16* woutb = (bf16*)ws;   ws += (size_t)DM * DM * 2;
  bf16* Qaug  = (bf16*)ws;   ws += (size_t)NH * S_PAD * AUGD * 2;
  bf16* Kaug  = (bf16*)ws;   ws += (size_t)NH * S_PAD * AUGD * 2;
  bf16* Vtb   = (bf16*)ws;   ws += (size_t)NH * S_PAD * HDIM * 2;
  bf16* attnb = (bf16*)ws;   ws += (size_t)S_LEN * DM * 2;
  float* Opart = (float*)ws; ws += (size_t)NH * NQT128 * MAXC * 8192 * 4;
  float* lpart = (float*)ws; ws += (size_t)NH * NQT128 * MAXC * 128 * 4;

  const int na4 = S_LEN * DM / 4, nb4 = QKV_STRIDE * DM / 4, nc4 = DM * DM / 4;
  const int ntot = na4 + nb4 + nc4;
  cvt3<<<dim3((ntot + 255) / 256), 256, 0, stream>>>(x, xb, na4, Wqkv, wqkvb, nb4, Wout, woutb, nc4);

  // 1) qkv = x @ Wqkv^T (bf16 out)
  gemm_bt<bf16><<<dim3(QKV_STRIDE / 64, NQT128), 256, 0, stream>>>(
      xb, wqkvb, qkvb, S_LEN, QKV_STRIDE, DM);
  // 2) build augmented Q/K (rope + bias factorization) and transposed V
  pack_aug<<<dim3(S_LEN), 512, 0, stream>>>(qkvb, pos, bx, by, bz, Qaug, Kaug);
  pack_v<<<dim3((S_LEN + 63) / 64, NH), 256, 0, stream>>>(qkvb, Vtb);
  // 3) split-K attention (bias inside the MFMA) + combine
  attn_split<<<dim3(MAXC, NQT128, NH), 256, 0, stream>>>(Qaug, Kaug, Vtb, attnb, Opart, lpart);
  attn_combine<<<dim3(NQT128 - 4, NH), 256, 0, stream>>>(Opart, lpart, attnb);
  // 4) out = attn @ Wout^T (fp32 out)
  gemm_bt<float><<<dim3(DM / 64, NQT128), 256, 0, stream>>>(
      attnb, woutb, out, S_LEN, DM, DM);
}